// Round 16
// baseline (158.985 us; speedup 1.0000x reference)
//
#include <hip/hip_runtime.h>
#include <math.h>

#define DD 512
#define NH 8
#define HD 64
#define NLQ 2048
#define NLK 8192
#define LOG2E 1.4426950408889634f
#define SCQ (0.125f * LOG2E)

typedef __attribute__((ext_vector_type(8))) short bf16x8;
typedef __attribute__((ext_vector_type(8))) unsigned short u16x8;
typedef __attribute__((ext_vector_type(4))) float f32x4;

#define MFMA16(a, b, c) __builtin_amdgcn_mfma_f32_16x16x32_bf16((a), (b), (c), 0, 0, 0)

__device__ __forceinline__ unsigned short f2bf(float x) {
    unsigned u = __builtin_bit_cast(unsigned, x);
    u += 0x7fffu + ((u >> 16) & 1u);
    return (unsigned short)(u >> 16);
}
__device__ __forceinline__ float bf2f(unsigned short h) {
    unsigned u = ((unsigned)h) << 16;
    return __builtin_bit_cast(float, u);
}
__device__ __forceinline__ unsigned short f2h(float x) {
    return __builtin_bit_cast(unsigned short, (_Float16)x);
}
__device__ __forceinline__ float h2f(unsigned short u) {
    return (float)__builtin_bit_cast(_Float16, u);
}
__device__ __forceinline__ int cvtpk(float a, float b) {
    int r;
    asm("v_cvt_pk_bf16_f32 %0, %1, %2" : "=v"(r) : "v"(a), "v"(b));
    return r;
}
__device__ __forceinline__ float max3f(float a, float b, float c) {
    return fmaxf(fmaxf(a, b), c);   // clang fuses to v_max3_f32
}
__device__ __forceinline__ float lobf(int w) {
    return __builtin_bit_cast(float, w << 16);
}
__device__ __forceinline__ float hibf(int w) {
    return __builtin_bit_cast(float, (int)(w & 0xffff0000));
}

// ---------------------------------------------------------------------------
// PREP (one launch, block-range fused):
//   blocks [0, 576):    QKV projection. bx=bid%144: <16 Q | <80 K | else V(tr).
//   blocks [576, 4672): bias+mask -> fp16 log2-units fragment pack.
// ---------------------------------------------------------------------------
#define NPROJ 576

__global__ __launch_bounds__(256) void prep(const float* __restrict__ Q,
                                            const float* __restrict__ K,
                                            const float* __restrict__ V,
                                            const float* __restrict__ Win,
                                            const float* __restrict__ bin,
                                            const float* __restrict__ bias,
                                            const int* __restrict__ mask,
                                            short* __restrict__ qhi,
                                            short* __restrict__ khi,
                                            short* __restrict__ vthi,
                                            unsigned short* __restrict__ bh)
{
    __shared__ __align__(16) short XsH[128 * 40];
    __shared__ __align__(16) short WsH[128 * 40];
    __shared__ __align__(16) short WsL[128 * 40];

    const int bid = blockIdx.x;
    if (bid >= NPROJ) {
        const int tid  = (bid - NPROJ) * 256 + threadIdx.x;
        const int tile = tid >> 6;          // (Qg*128 + kt)
        const int l    = tid & 63;
        const int q    = (tile >> 7) * 16 + (l & 15);
        const int kb   = (tile & 127) * 64 + 4 * (l >> 4);
        u16x8 o0v, o1v;
#pragma unroll
        for (int j = 0; j < 4; ++j) {
            const float4 bv = *(const float4*)&bias[(size_t)q * NLK + kb + 16 * j];
            const int4   mv = *(const int4*)&mask[kb + 16 * j];
            const float a[4] = {bv.x, bv.y, bv.z, bv.w};
            const int   m[4] = {mv.x, mv.y, mv.z, mv.w};
#pragma unroll
            for (int r = 0; r < 4; ++r) {
                const float v = (a[r] - 10000.f * (float)m[r]) * LOG2E;
                const int idx = j * 4 + r;
                if (idx < 8) o0v[idx] = f2h(v);
                else         o1v[idx - 8] = f2h(v);
            }
        }
        const size_t base = ((size_t)tid) * 16;
        *(u16x8*)&bh[base] = o0v;
        *(u16x8*)&bh[base + 8] = o1v;
        return;
    }

    const int o0 = (bid / 144) * 128;
    const int bx = bid % 144;
    const float* X; const float* Wf; const float* b; short* out;
    int r0; float scale; int tr;
    if (bx < 16)      { X = Q; r0 = bx * 128;        Wf = Win;               b = bin;          out = qhi;  scale = SCQ; tr = 0; }
    else if (bx < 80) { X = K; r0 = (bx - 16) * 128; Wf = Win + DD * DD;     b = bin + DD;     out = khi;  scale = 1.f; tr = 0; }
    else              { X = V; r0 = (bx - 80) * 128; Wf = Win + 2 * DD * DD; b = bin + 2 * DD; out = vthi; scale = 1.f; tr = 1; }

    const int t    = threadIdx.x;
    const int wid  = t >> 6;
    const int lane = t & 63;
    const int g  = lane >> 4;
    const int c  = lane & 15;
    const int wr = wid >> 1;
    const int wc = wid & 1;
    const int srow = t >> 1;
    const int sk   = (t & 1) * 16;

    float4 xf[4], wf[4];
    auto ld = [&](int kc) {
#pragma unroll
        for (int i = 0; i < 4; ++i) {
            xf[i] = *(const float4*)&X[(size_t)(r0 + srow) * DD + kc + sk + 4 * i];
            wf[i] = *(const float4*)&Wf[(size_t)(o0 + srow) * DD + kc + sk + 4 * i];
        }
    };
    auto st = [&]() {
#pragma unroll
        for (int i = 0; i < 2; ++i) {
            int4 xw;
            xw.x = cvtpk(xf[2 * i].x, xf[2 * i].y);
            xw.y = cvtpk(xf[2 * i].z, xf[2 * i].w);
            xw.z = cvtpk(xf[2 * i + 1].x, xf[2 * i + 1].y);
            xw.w = cvtpk(xf[2 * i + 1].z, xf[2 * i + 1].w);
            *(int4*)&XsH[srow * 40 + sk + 8 * i] = xw;
            const float4 a = wf[2 * i], bb = wf[2 * i + 1];
            int4 hw;
            hw.x = cvtpk(a.x, a.y);
            hw.y = cvtpk(a.z, a.w);
            hw.z = cvtpk(bb.x, bb.y);
            hw.w = cvtpk(bb.z, bb.w);
            int4 lw;
            lw.x = cvtpk(a.x - lobf(hw.x), a.y - hibf(hw.x));
            lw.y = cvtpk(a.z - lobf(hw.y), a.w - hibf(hw.y));
            lw.z = cvtpk(bb.x - lobf(hw.z), bb.y - hibf(hw.z));
            lw.w = cvtpk(bb.z - lobf(hw.w), bb.w - hibf(hw.w));
            *(int4*)&WsH[srow * 40 + sk + 8 * i] = hw;
            *(int4*)&WsL[srow * 40 + sk + 8 * i] = lw;
        }
    };

    f32x4 acc[4][4];
#pragma unroll
    for (int i = 0; i < 4; ++i)
#pragma unroll
        for (int j = 0; j < 4; ++j) acc[i][j] = (f32x4){0.f, 0.f, 0.f, 0.f};

    ld(0);
    for (int kc = 0; kc < DD; kc += 32) {
        __syncthreads();
        st();
        __syncthreads();
        if (kc + 32 < DD) ld(kc + 32);

        bf16x8 ah[4], bhf[4], blf[4];
#pragma unroll
        for (int qg = 0; qg < 4; ++qg)
            ah[qg] = *(const bf16x8*)&XsH[(64 * wr + 16 * qg + c) * 40 + 8 * g];
#pragma unroll
        for (int og = 0; og < 4; ++og) {
            const int adr = (64 * wc + 16 * og + c) * 40 + 8 * g;
            bhf[og] = *(const bf16x8*)&WsH[adr];
            blf[og] = *(const bf16x8*)&WsL[adr];
        }
#pragma unroll
        for (int qg = 0; qg < 4; ++qg)
#pragma unroll
            for (int og = 0; og < 4; ++og) {
                acc[qg][og] = MFMA16(ah[qg], bhf[og], acc[qg][og]);
                acc[qg][og] = MFMA16(ah[qg], blf[og], acc[qg][og]);
            }
    }

#pragma unroll
    for (int qg = 0; qg < 4; ++qg)
#pragma unroll
        for (int og = 0; og < 4; ++og) {
            const int col = o0 + 64 * wc + 16 * og + c;
            const float bo = b[col];
#pragma unroll
            for (int r = 0; r < 4; ++r) {
                const int row = r0 + 64 * wr + 16 * qg + 4 * g + r;
                const float v = (acc[qg][og][r] + bo) * scale;
                if (tr) out[(size_t)col * NLK + row] = (short)f2bf(v);
                else    out[(size_t)row * DD + col]  = (short)f2bf(v);
            }
        }
}

// ---------------------------------------------------------------------------
// Out-projection: 64x64 tiles, X hi/lo, W f32 -> hi/lo in staging, 3-MFMA.
// ---------------------------------------------------------------------------
__global__ __launch_bounds__(256) void gemm_out(const short* __restrict__ Xhi,
                                                const short* __restrict__ Xlo,
                                                const float* __restrict__ Wf,
                                                const float* __restrict__ b,
                                                float* __restrict__ Y)
{
    __shared__ __align__(16) short XsH[64 * 40];
    __shared__ __align__(16) short XsL[64 * 40];
    __shared__ __align__(16) short WsH[64 * 40];
    __shared__ __align__(16) short WsL[64 * 40];

    const int r0 = blockIdx.x * 64;
    const int o0 = blockIdx.y * 64;
    const int t    = threadIdx.x;
    const int wid  = t >> 6;
    const int lane = t & 63;
    const int g  = lane >> 4;
    const int c  = lane & 15;
    const int srow = t >> 2;
    const int sc8  = (t & 3) * 8;

    bf16x8 pxh, pxl;
    float4 wf0, wf1;
    auto ld = [&](int kc) {
        pxh = *(const bf16x8*)&Xhi[(size_t)(r0 + srow) * DD + kc + sc8];
        pxl = *(const bf16x8*)&Xlo[(size_t)(r0 + srow) * DD + kc + sc8];
        wf0 = *(const float4*)&Wf[(size_t)(o0 + srow) * DD + kc + sc8];
        wf1 = *(const float4*)&Wf[(size_t)(o0 + srow) * DD + kc + sc8 + 4];
    };
    auto st = [&]() {
        *(bf16x8*)&XsH[srow * 40 + sc8] = pxh;
        *(bf16x8*)&XsL[srow * 40 + sc8] = pxl;
        int4 hw;
        hw.x = cvtpk(wf0.x, wf0.y);
        hw.y = cvtpk(wf0.z, wf0.w);
        hw.z = cvtpk(wf1.x, wf1.y);
        hw.w = cvtpk(wf1.z, wf1.w);
        int4 lw;
        lw.x = cvtpk(wf0.x - lobf(hw.x), wf0.y - hibf(hw.x));
        lw.y = cvtpk(wf0.z - lobf(hw.y), wf0.w - hibf(hw.y));
        lw.z = cvtpk(wf1.x - lobf(hw.z), wf1.y - hibf(hw.z));
        lw.w = cvtpk(wf1.z - lobf(hw.w), wf1.w - hibf(hw.w));
        *(int4*)&WsH[srow * 40 + sc8] = hw;
        *(int4*)&WsL[srow * 40 + sc8] = lw;
    };

    f32x4 acc[4];
#pragma unroll
    for (int n = 0; n < 4; ++n) acc[n] = (f32x4){0.f, 0.f, 0.f, 0.f};

    ld(0);
    for (int kc = 0; kc < DD; kc += 32) {
        __syncthreads();
        st();
        __syncthreads();
        if (kc + 32 < DD) ld(kc + 32);

        bf16x8 ah, al, bh[4], bl[4];
        ah = *(const bf16x8*)&XsH[(wid * 16 + c) * 40 + 8 * g];
        al = *(const bf16x8*)&XsL[(wid * 16 + c) * 40 + 8 * g];
#pragma unroll
        for (int n = 0; n < 4; ++n) {
            const int adr = (16 * n + c) * 40 + 8 * g;
            bh[n] = *(const bf16x8*)&WsH[adr];
            bl[n] = *(const bf16x8*)&WsL[adr];
        }
#pragma unroll
        for (int n = 0; n < 4; ++n) {
            acc[n] = MFMA16(ah, bh[n], acc[n]);
            acc[n] = MFMA16(ah, bl[n], acc[n]);
            acc[n] = MFMA16(al, bh[n], acc[n]);
        }
    }

#pragma unroll
    for (int n = 0; n < 4; ++n) {
        const int col = o0 + 16 * n + c;
        const float bo = b[col];
#pragma unroll
        for (int r = 0; r < 4; ++r)
            Y[(size_t)(r0 + wid * 16 + 4 * g + r) * DD + col] = acc[n][r] + bo;
    }
}

// ---------------------------------------------------------------------------
// MFMA flash attention. R16: 2 q-groups per wave (each K/V fragment read once
// feeds both groups' MFMAs; DS ops/q 1.5 -> 1.0) in 256-thread 4-wave blocks
// with launch_bounds(256,1): VGPR cap 512 -- R15's (512,4) envelope made the
// compiler allocate 64 VGPR and SPILL (WRITE_SIZE 36.9 MB). QT=128, grid 1024
// (8h x 16qt x 8kc). LDS 40 KB. Spill detector: WRITE_SIZE ~17 MB = healthy.
// ---------------------------------------------------------------------------
#define QT 128
#define KT 64
#define NKC 8
#define CHUNK (NLK / NKC)
#define NT (CHUNK / KT)
#define BOFF (128 * 1024)   // biash element offset between adjacent q-groups

__global__ __launch_bounds__(256, 1) void attn_mfma(const short* __restrict__ qhi,
                                                    const short* __restrict__ khi,
                                                    const short* __restrict__ vthi,
                                                    const unsigned short* __restrict__ biash,
                                                    unsigned short* __restrict__ macc,
                                                    float2* __restrict__ mlb)
{
    __shared__ __align__(16) short ksh[2 * KT * HD];   // 16 KB
    __shared__ __align__(16) short vth[2 * KT * HD];   // 16 KB
    __shared__ __align__(16) short psh[4 * 16 * KT];   // 8 KB, per-wave 2 KB

    const int id = blockIdx.x;          // h*128 + qt*8 + kc
    const int h  = id >> 7;
    const int qt = (id >> 3) & 15;
    const int kc = id & 7;
    const int q0 = qt * QT;
    const int k0 = kc * CHUNK;

    const int t    = threadIdx.x;
    const int wid  = t >> 6;            // 0..3
    const int lane = t & 63;
    const int g  = lane >> 4;
    const int cl = lane & 15;
    const int swc = ((cl & 7) << 3);

    // Q fragments for both 16-q groups (A: rows q0+wid*32+cl, B: +16)
    bf16x8 qaA[2], qaB[2];
    {
        const size_t qrA = (size_t)(q0 + wid * 32 + cl) * DD + h * HD;
        qaA[0] = *(const bf16x8*)&qhi[qrA + 8 * g];
        qaA[1] = *(const bf16x8*)&qhi[qrA + 32 + 8 * g];
        qaB[0] = *(const bf16x8*)&qhi[qrA + 16 * DD + 8 * g];
        qaB[1] = *(const bf16x8*)&qhi[qrA + 16 * DD + 32 + 8 * g];
    }

    const int v0 = (8 * g) ^ swc;
    const short* kbA0 = &ksh[cl * HD + v0];
    const short* kbB0 = &ksh[cl * HD + (v0 ^ 32)];
    const short* kbA1 = kbA0 + KT * HD;
    const short* kbB1 = kbB0 + KT * HD;
    const short* vbA0 = &vth[cl * HD + v0];
    const short* vbB0 = &vth[cl * HD + (v0 ^ 32)];
    const short* vbA1 = vbA0 + KT * HD;
    const short* vbB1 = vbB0 + KT * HD;

    // staging for 256 threads: row kr0 = t>>2 (0..63), cols db0 = (t&3)*16
    // two 8-short granules db0, db0+8, each XOR-swizzled by row.
    const int kr0 = t >> 2;
    const int db0 = (t & 3) * 16;
    const int sw0 = ((kr0 & 7) << 3);
    short* wka0 = &ksh[kr0 * HD + (db0 ^ sw0)];
    short* wkb0 = &ksh[kr0 * HD + ((db0 + 8) ^ sw0)];
    short* wva0 = &vth[kr0 * HD + (db0 ^ sw0)];
    short* wvb0 = &vth[kr0 * HD + ((db0 + 8) ^ sw0)];

    // per-wave P scratch (2 KB), sequentially reused by groups A then B
    short* psw = &psh[wid * (16 * KT)];
    short* pw0 = &psw[cl * KT + (( 0 + 4 * g) ^ swc)];
    short* pw1 = &psw[cl * KT + ((16 + 4 * g) ^ swc)];
    short* pw2 = &psw[cl * KT + ((32 + 4 * g) ^ swc)];
    short* pw3 = &psw[cl * KT + ((48 + 4 * g) ^ swc)];
    const short* pr0 = &psw[cl * KT + ((8 * g) ^ swc)];
    const short* pr1 = &psw[cl * KT + ((32 + 8 * g) ^ swc)];

    const short* kgp = khi + (size_t)(k0 + kr0) * DD + h * HD + db0;
    const short* vgp = vthi + (size_t)(h * HD + kr0) * NLK + k0 + db0;
    // group A q-group index = qt*8 + wid*2; group B = +1 (offset BOFF)
    const unsigned short* bgp =
        biash + (((size_t)(qt * 8 + wid * 2) * 128 + kc * NT) << 10) + lane * 16;

    bf16x8 rkh[2], rvh[2];
    u16x8 bpA0, bpA1, bpB0, bpB1;
    rkh[0] = *(const bf16x8*)kgp;
    rkh[1] = *(const bf16x8*)(kgp + 8);  kgp += (size_t)KT * DD;
    rvh[0] = *(const bf16x8*)vgp;
    rvh[1] = *(const bf16x8*)(vgp + 8);  vgp += KT;
    bpA0 = *(const u16x8*)bgp;
    bpA1 = *(const u16x8*)(bgp + 8);
    bpB0 = *(const u16x8*)(bgp + BOFF);
    bpB1 = *(const u16x8*)(bgp + BOFF + 8);
    bgp += 1024;

    bf16x8 ones;
#pragma unroll
    for (int i = 0; i < 8; ++i) ones[i] = (short)0x3F80;

    f32x4 accA[4], accB[4];
    f32x4 lacA = (f32x4){0.f, 0.f, 0.f, 0.f};
    f32x4 lacB = (f32x4){0.f, 0.f, 0.f, 0.f};
#pragma unroll
    for (int n = 0; n < 4; ++n) {
        accA[n] = (f32x4){0.f, 0.f, 0.f, 0.f};
        accB[n] = (f32x4){0.f, 0.f, 0.f, 0.f};
    }
    float mA = -1e30f, mB = -1e30f;

    auto softmax_pack = [&](f32x4 (&sc)[4], f32x4 (&acc)[4], f32x4 &lac,
                            float &mm, bf16x8 (&pa)[2]) {
        const float t0 = max3f(sc[0][0], sc[0][1], sc[0][2]);
        const float t1 = max3f(sc[0][3], sc[1][0], sc[1][1]);
        const float t2 = max3f(sc[1][2], sc[1][3], sc[2][0]);
        const float t3 = max3f(sc[2][1], sc[2][2], sc[2][3]);
        const float t4 = max3f(sc[3][0], sc[3][1], sc[3][2]);
        float tm = max3f(max3f(t0, t1, t2), max3f(t3, t4, sc[3][3]), -1e30f);
        tm = fmaxf(tm, __shfl_xor(tm, 16));
        tm = fmaxf(tm, __shfl_xor(tm, 32));
        if (!__all(tm - mm <= 11.5f)) {
            const float mn = fmaxf(mm, tm);
            const float al = exp2f(mm - mn);
            float alr[4];
#pragma unroll
            for (int r = 0; r < 4; ++r) alr[r] = __shfl(al, 4 * g + r);
#pragma unroll
            for (int n = 0; n < 4; ++n)
#pragma unroll
                for (int r = 0; r < 4; ++r) acc[n][r] *= alr[r];
#pragma unroll
            for (int r = 0; r < 4; ++r) lac[r] *= alr[r];
            mm = mn;
        }
#pragma unroll
        for (int j = 0; j < 4; ++j)
#pragma unroll
            for (int r = 0; r < 4; ++r)
                sc[j][r] = exp2f(sc[j][r] - mm);
        *(int2*)pw0 = make_int2(cvtpk(sc[0][0], sc[0][1]), cvtpk(sc[0][2], sc[0][3]));
        *(int2*)pw1 = make_int2(cvtpk(sc[1][0], sc[1][1]), cvtpk(sc[1][2], sc[1][3]));
        *(int2*)pw2 = make_int2(cvtpk(sc[2][0], sc[2][1]), cvtpk(sc[2][2], sc[2][3]));
        *(int2*)pw3 = make_int2(cvtpk(sc[3][0], sc[3][1]), cvtpk(sc[3][2], sc[3][3]));
        pa[0] = *(const bf16x8*)pr0;
        pa[1] = *(const bf16x8*)pr1;
    };

    for (int it = 0; it < NT; ++it) {
        const int p = it & 1;
        const int po = p * KT * HD;
        const short* kA = kbA0 + po;  // == p ? kbA1 : kbA0 (cheap add form)
        const short* kB = kbB0 + po;
        const short* vA = vbA0 + po;
        const short* vB = vbB0 + po;
        (void)kbA1; (void)kbB1; (void)vbA1; (void)vbB1;

        *(bf16x8*)(wka0 + po) = rkh[0];
        *(bf16x8*)(wkb0 + po) = rkh[1];
        *(bf16x8*)(wva0 + po) = rvh[0];
        *(bf16x8*)(wvb0 + po) = rvh[1];
        __syncthreads();
        if (it + 1 < NT) {
            rkh[0] = *(const bf16x8*)kgp;
            rkh[1] = *(const bf16x8*)(kgp + 8);  kgp += (size_t)KT * DD;
            rvh[0] = *(const bf16x8*)vgp;
            rvh[1] = *(const bf16x8*)(vgp + 8);  vgp += KT;
        }

        // ---- C-in = bias fragments ----
        f32x4 scA[4], scB[4];
#pragma unroll
        for (int j = 0; j < 4; ++j)
#pragma unroll
            for (int r = 0; r < 4; ++r) {
                const int i = j * 4 + r;
                scA[j][r] = h2f((i < 8) ? (unsigned short)bpA0[i]
                                        : (unsigned short)bpA1[i - 8]);
                scB[j][r] = h2f((i < 8) ? (unsigned short)bpB0[i]
                                        : (unsigned short)bpB1[i - 8]);
            }

        // ---- swapped QK^T: each kf read once, feeds both q-groups ----
        __builtin_amdgcn_s_setprio(1);
#pragma unroll
        for (int j = 0; j < 4; ++j) {
            const bf16x8 kf0 = *(const bf16x8*)(kA + j * 16 * HD);
            const bf16x8 kf1 = *(const bf16x8*)(kB + j * 16 * HD);
            scA[j] = MFMA16(kf0, qaA[0], scA[j]);
            scA[j] = MFMA16(kf1, qaA[1], scA[j]);
            scB[j] = MFMA16(kf0, qaB[0], scB[j]);
            scB[j] = MFMA16(kf1, qaB[1], scB[j]);
        }
        __builtin_amdgcn_s_setprio(0);

        // ---- softmax + pack per group (psh reused; per-wave in-order DS) ----
        bf16x8 paA[2], paB[2];
        softmax_pack(scA, accA, lacA, mA, paA);
        softmax_pack(scB, accB, lacB, mB, paB);

        // ---- PV + l-sum: each vh read once, feeds both q-groups ----
        __builtin_amdgcn_s_setprio(1);
#pragma unroll
        for (int n = 0; n < 4; ++n) {
            const bf16x8 vh0 = *(const bf16x8*)(vA + n * 16 * HD);
            const bf16x8 vh1 = *(const bf16x8*)(vB + n * 16 * HD);
            accA[n] = MFMA16(paA[0], vh0, accA[n]);
            accA[n] = MFMA16(paA[1], vh1, accA[n]);
            accB[n] = MFMA16(paB[0], vh0, accB[n]);
            accB[n] = MFMA16(paB[1], vh1, accB[n]);
        }
        lacA = MFMA16(paA[0], ones, lacA);
        lacA = MFMA16(paA[1], ones, lacA);
        lacB = MFMA16(paB[0], ones, lacB);
        lacB = MFMA16(paB[1], ones, lacB);
        __builtin_amdgcn_s_setprio(0);

        // ---- bias prefetch for next tile (after PV: bp not co-live with sc) ----
        if (it + 1 < NT) {
            bpA0 = *(const u16x8*)bgp;
            bpA1 = *(const u16x8*)(bgp + 8);
            bpB0 = *(const u16x8*)(bgp + BOFF);
            bpB1 = *(const u16x8*)(bgp + BOFF + 8);
            bgp += 1024;
        }
    }

    // ---- epilogue per group: normalize, store macc; route l to g==0 lanes ----
    auto epilogue = [&](f32x4 (&acc)[4], f32x4 &lac, float mm, int qbase) {
        f32x4 linv;
#pragma unroll
        for (int r = 0; r < 4; ++r) linv[r] = 1.f / lac[r];
#pragma unroll
        for (int r = 0; r < 4; ++r) {
            const int q = qbase + 4 * g + r;
            const size_t base = ((size_t)(kc * NH + h) * NLQ + q) * HD;
#pragma unroll
            for (int n = 0; n < 4; ++n)
                macc[base + 16 * n + cl] = f2h(acc[n][r] * linv[r]);
        }
        const int srcl = ((cl >> 2) << 4) + cl;
        const float lc0 = __shfl(lac[0], srcl);
        const float lc1 = __shfl(lac[1], srcl);
        const float lc2 = __shfl(lac[2], srcl);
        const float lc3 = __shfl(lac[3], srcl);
        const int rr = cl & 3;
        const float lq = rr == 0 ? lc0 : rr == 1 ? lc1 : rr == 2 ? lc2 : lc3;
        if (g == 0)
            mlb[(size_t)(kc * NH + h) * NLQ + qbase + cl] = make_float2(mm, lq);
    };
    epilogue(accA, lacA, mA, q0 + wid * 32);
    epilogue(accB, lacB, mB, q0 + wid * 32 + 16);
}

// ---------------------------------------------------------------------------
// Combine: partials pre-normalized; weight = exp2(m_c - M) * l_c.
// ---------------------------------------------------------------------------
__global__ __launch_bounds__(256) void attn_combine(const unsigned short* __restrict__ macc,
                                                    const float2* __restrict__ mlb,
                                                    short* __restrict__ aohi,
                                                    short* __restrict__ aolo)
{
    const int row = blockIdx.x * 4 + (threadIdx.x >> 6);  // h*NLQ + q
    const int d   = threadIdx.x & 63;
    float m[NKC], l[NKC];
#pragma unroll
    for (int c = 0; c < NKC; ++c) {
        const float2 v = mlb[(size_t)c * NH * NLQ + row];
        m[c] = v.x; l[c] = v.y;
    }
    float M = m[0];
#pragma unroll
    for (int c = 1; c < NKC; ++c) M = fmaxf(M, m[c]);
    float w[NKC], L = 0.f;
#pragma unroll
    for (int c = 0; c < NKC; ++c) { w[c] = exp2f(m[c] - M) * l[c]; L += w[c]; }
    float s = 0.f;
#pragma unroll
    for (int c = 0; c < NKC; ++c)
        s += h2f(macc[((size_t)c * NH * NLQ + row) * HD + d]) * w[c];
    const float v = s / L;
    const int hh = row >> 11;
    const int q  = row & (NLQ - 1);
    const size_t o = (size_t)q * DD + hh * HD + d;
    const unsigned short hb = f2bf(v);
    aohi[o] = (short)hb;
    aolo[o] = (short)f2bf(v - bf2f(hb));
}

extern "C" void kernel_launch(void* const* d_in, const int* in_sizes, int n_in,
                              void* d_out, int out_size, void* d_ws, size_t ws_size,
                              hipStream_t stream)
{
    (void)in_sizes; (void)n_in; (void)out_size; (void)ws_size;
    const float* Q    = (const float*)d_in[0];
    const float* K    = (const float*)d_in[1];
    const float* V    = (const float*)d_in[2];
    const int*   mask = (const int*)d_in[3];
    const float* bias = (const float*)d_in[4];
    const float* Win  = (const float*)d_in[5];
    const float* bin  = (const float*)d_in[6];
    const float* Wout = (const float*)d_in[7];
    const float* bout = (const float*)d_in[8];
    float* out = (float*)d_out;

    // ---- workspace (~72 MB flat) ----
    short* qhi_  = (short*)d_ws;                                // 2 MB
    short* khi_  = qhi_  + (size_t)NLQ * DD;                    // 8 MB
    short* vthi_ = khi_  + (size_t)NLK * DD;                    // 8 MB
    unsigned short* biash_ = (unsigned short*)(vthi_ + (size_t)NLK * DD); // 32 MB
    unsigned short* macc_  = biash_ + (size_t)NLQ * NLK;        // 16.8 MB
    float2* ml_  = (float2*)(macc_ + (size_t)NKC * NH * NLQ * HD);  // 1 MB
    short* aohi_ = (short*)(ml_ + (size_t)NKC * NH * NLQ);      // 2 MB
    short* aolo_ = aohi_ + (size_t)NLQ * DD;                    // 2 MB

    // 1) fused prep: QKV projection (576 blocks) + bias pack (4096 blocks)
    prep<<<dim3(NPROJ + 4096), 256, 0, stream>>>(Q, K, V, Win, bin, bias, mask,
                                                 qhi_, khi_, vthi_, biash_);

    // 2) attention (k-split NKC=8, QT=128, 32 q per wave, 4-wave blocks)
    attn_mfma<<<dim3(NH * 16 * NKC), 256, 0, stream>>>(qhi_, khi_, vthi_, biash_, macc_, ml_);

    // 3) combine partials -> ao (bf16 hi/lo)
    attn_combine<<<dim3(NH * NLQ / 4), 256, 0, stream>>>(macc_, ml_, aohi_, aolo_);

    // 4) out projection (W f32 staged)
    gemm_out<<<dim3(NLQ / 64, DD / 64), 256, 0, stream>>>(aohi_, aolo_, Wout, bout, out);
}

// Round 17
// 145.072 us; speedup vs baseline: 1.0959x; 1.0959x over previous
//
#include <hip/hip_runtime.h>
#include <math.h>

#define DD 512
#define NH 8
#define HD 64
#define NLQ 2048
#define NLK 8192
#define LOG2E 1.4426950408889634f
#define SCQ (0.125f * LOG2E)

typedef __attribute__((ext_vector_type(8))) short bf16x8;
typedef __attribute__((ext_vector_type(8))) unsigned short u16x8;
typedef __attribute__((ext_vector_type(4))) float f32x4;

#define MFMA16(a, b, c) __builtin_amdgcn_mfma_f32_16x16x32_bf16((a), (b), (c), 0, 0, 0)

__device__ __forceinline__ unsigned short f2bf(float x) {
    unsigned u = __builtin_bit_cast(unsigned, x);
    u += 0x7fffu + ((u >> 16) & 1u);
    return (unsigned short)(u >> 16);
}
__device__ __forceinline__ float bf2f(unsigned short h) {
    unsigned u = ((unsigned)h) << 16;
    return __builtin_bit_cast(float, u);
}
__device__ __forceinline__ unsigned short f2h(float x) {
    return __builtin_bit_cast(unsigned short, (_Float16)x);
}
__device__ __forceinline__ float h2f(unsigned short u) {
    return (float)__builtin_bit_cast(_Float16, u);
}
__device__ __forceinline__ int cvtpk(float a, float b) {
    int r;
    asm("v_cvt_pk_bf16_f32 %0, %1, %2" : "=v"(r) : "v"(a), "v"(b));
    return r;
}
__device__ __forceinline__ float max3f(float a, float b, float c) {
    return fmaxf(fmaxf(a, b), c);   // clang fuses to v_max3_f32
}
// bf2f of the low/high bf16 halves of a cvtpk-packed int
__device__ __forceinline__ float lobf(int w) {
    return __builtin_bit_cast(float, w << 16);
}
__device__ __forceinline__ float hibf(int w) {
    return __builtin_bit_cast(float, (int)(w & 0xffff0000));
}

// ---------------------------------------------------------------------------
// PREP (one launch, block-range fused):
//   blocks [0, 576):    QKV projection. bx=bid%144: <16 Q | <80 K | else V(tr).
//   blocks [576, 4672): bias+mask -> fp16 log2-units fragment pack.
// ---------------------------------------------------------------------------
#define NPROJ 576

__global__ __launch_bounds__(256) void prep(const float* __restrict__ Q,
                                            const float* __restrict__ K,
                                            const float* __restrict__ V,
                                            const float* __restrict__ Win,
                                            const float* __restrict__ bin,
                                            const float* __restrict__ bias,
                                            const int* __restrict__ mask,
                                            short* __restrict__ qhi,
                                            short* __restrict__ khi,
                                            short* __restrict__ vthi,
                                            unsigned short* __restrict__ bh)
{
    __shared__ __align__(16) short XsH[128 * 40];
    __shared__ __align__(16) short WsH[128 * 40];
    __shared__ __align__(16) short WsL[128 * 40];

    const int bid = blockIdx.x;
    if (bid >= NPROJ) {
        // ---- bias pack path (grid-fused; no LDS use) ----
        const int tid  = (bid - NPROJ) * 256 + threadIdx.x;
        const int tile = tid >> 6;          // (Qg*128 + kt)
        const int l    = tid & 63;
        const int q    = (tile >> 7) * 16 + (l & 15);
        const int kb   = (tile & 127) * 64 + 4 * (l >> 4);
        u16x8 o0v, o1v;
#pragma unroll
        for (int j = 0; j < 4; ++j) {
            const float4 bv = *(const float4*)&bias[(size_t)q * NLK + kb + 16 * j];
            const int4   mv = *(const int4*)&mask[kb + 16 * j];
            const float a[4] = {bv.x, bv.y, bv.z, bv.w};
            const int   m[4] = {mv.x, mv.y, mv.z, mv.w};
#pragma unroll
            for (int r = 0; r < 4; ++r) {
                const float v = (a[r] - 10000.f * (float)m[r]) * LOG2E;
                const int idx = j * 4 + r;
                if (idx < 8) o0v[idx] = f2h(v);
                else         o1v[idx - 8] = f2h(v);
            }
        }
        const size_t base = ((size_t)tid) * 16;
        *(u16x8*)&bh[base] = o0v;
        *(u16x8*)&bh[base + 8] = o1v;
        return;
    }

    // ---- QKV projection path ----
    const int o0 = (bid / 144) * 128;
    const int bx = bid % 144;
    const float* X; const float* Wf; const float* b; short* out;
    int r0; float scale; int tr;
    if (bx < 16)      { X = Q; r0 = bx * 128;        Wf = Win;               b = bin;          out = qhi;  scale = SCQ; tr = 0; }
    else if (bx < 80) { X = K; r0 = (bx - 16) * 128; Wf = Win + DD * DD;     b = bin + DD;     out = khi;  scale = 1.f; tr = 0; }
    else              { X = V; r0 = (bx - 80) * 128; Wf = Win + 2 * DD * DD; b = bin + 2 * DD; out = vthi; scale = 1.f; tr = 1; }

    const int t    = threadIdx.x;
    const int wid  = t >> 6;
    const int lane = t & 63;
    const int g  = lane >> 4;
    const int c  = lane & 15;
    const int wr = wid >> 1;
    const int wc = wid & 1;
    const int srow = t >> 1;
    const int sk   = (t & 1) * 16;

    float4 xf[4], wf[4];
    auto ld = [&](int kc) {
#pragma unroll
        for (int i = 0; i < 4; ++i) {
            xf[i] = *(const float4*)&X[(size_t)(r0 + srow) * DD + kc + sk + 4 * i];
            wf[i] = *(const float4*)&Wf[(size_t)(o0 + srow) * DD + kc + sk + 4 * i];
        }
    };
    auto st = [&]() {
#pragma unroll
        for (int i = 0; i < 2; ++i) {
            int4 xw;
            xw.x = cvtpk(xf[2 * i].x, xf[2 * i].y);
            xw.y = cvtpk(xf[2 * i].z, xf[2 * i].w);
            xw.z = cvtpk(xf[2 * i + 1].x, xf[2 * i + 1].y);
            xw.w = cvtpk(xf[2 * i + 1].z, xf[2 * i + 1].w);
            *(int4*)&XsH[srow * 40 + sk + 8 * i] = xw;
            const float4 a = wf[2 * i], bb = wf[2 * i + 1];
            int4 hw;
            hw.x = cvtpk(a.x, a.y);
            hw.y = cvtpk(a.z, a.w);
            hw.z = cvtpk(bb.x, bb.y);
            hw.w = cvtpk(bb.z, bb.w);
            int4 lw;
            lw.x = cvtpk(a.x - lobf(hw.x), a.y - hibf(hw.x));
            lw.y = cvtpk(a.z - lobf(hw.y), a.w - hibf(hw.y));
            lw.z = cvtpk(bb.x - lobf(hw.z), bb.y - hibf(hw.z));
            lw.w = cvtpk(bb.z - lobf(hw.w), bb.w - hibf(hw.w));
            *(int4*)&WsH[srow * 40 + sk + 8 * i] = hw;
            *(int4*)&WsL[srow * 40 + sk + 8 * i] = lw;
        }
    };

    f32x4 acc[4][4];
#pragma unroll
    for (int i = 0; i < 4; ++i)
#pragma unroll
        for (int j = 0; j < 4; ++j) acc[i][j] = (f32x4){0.f, 0.f, 0.f, 0.f};

    ld(0);
    for (int kc = 0; kc < DD; kc += 32) {
        __syncthreads();
        st();
        __syncthreads();
        if (kc + 32 < DD) ld(kc + 32);

        bf16x8 ah[4], bhf[4], blf[4];
#pragma unroll
        for (int qg = 0; qg < 4; ++qg)
            ah[qg] = *(const bf16x8*)&XsH[(64 * wr + 16 * qg + c) * 40 + 8 * g];
#pragma unroll
        for (int og = 0; og < 4; ++og) {
            const int adr = (64 * wc + 16 * og + c) * 40 + 8 * g;
            bhf[og] = *(const bf16x8*)&WsH[adr];
            blf[og] = *(const bf16x8*)&WsL[adr];
        }
#pragma unroll
        for (int qg = 0; qg < 4; ++qg)
#pragma unroll
            for (int og = 0; og < 4; ++og) {
                acc[qg][og] = MFMA16(ah[qg], bhf[og], acc[qg][og]);
                acc[qg][og] = MFMA16(ah[qg], blf[og], acc[qg][og]);
            }
    }

#pragma unroll
    for (int qg = 0; qg < 4; ++qg)
#pragma unroll
        for (int og = 0; og < 4; ++og) {
            const int col = o0 + 64 * wc + 16 * og + c;
            const float bo = b[col];
#pragma unroll
            for (int r = 0; r < 4; ++r) {
                const int row = r0 + 64 * wr + 16 * qg + 4 * g + r;
                const float v = (acc[qg][og][r] + bo) * scale;
                if (tr) out[(size_t)col * NLK + row] = (short)f2bf(v);
                else    out[(size_t)row * DD + col]  = (short)f2bf(v);
            }
        }
}

// ---------------------------------------------------------------------------
// Out-projection: 64x64 tiles (256 blocks), X hi/lo (from combine),
// W f32 -> hi/lo split in staging, 3-MFMA, f32 out.
// ---------------------------------------------------------------------------
__global__ __launch_bounds__(256) void gemm_out(const short* __restrict__ Xhi,
                                                const short* __restrict__ Xlo,
                                                const float* __restrict__ Wf,
                                                const float* __restrict__ b,
                                                float* __restrict__ Y)
{
    __shared__ __align__(16) short XsH[64 * 40];
    __shared__ __align__(16) short XsL[64 * 40];
    __shared__ __align__(16) short WsH[64 * 40];
    __shared__ __align__(16) short WsL[64 * 40];

    const int r0 = blockIdx.x * 64;
    const int o0 = blockIdx.y * 64;
    const int t    = threadIdx.x;
    const int wid  = t >> 6;
    const int lane = t & 63;
    const int g  = lane >> 4;
    const int c  = lane & 15;
    const int srow = t >> 2;
    const int sc8  = (t & 3) * 8;

    bf16x8 pxh, pxl;
    float4 wf0, wf1;
    auto ld = [&](int kc) {
        pxh = *(const bf16x8*)&Xhi[(size_t)(r0 + srow) * DD + kc + sc8];
        pxl = *(const bf16x8*)&Xlo[(size_t)(r0 + srow) * DD + kc + sc8];
        wf0 = *(const float4*)&Wf[(size_t)(o0 + srow) * DD + kc + sc8];
        wf1 = *(const float4*)&Wf[(size_t)(o0 + srow) * DD + kc + sc8 + 4];
    };
    auto st = [&]() {
        *(bf16x8*)&XsH[srow * 40 + sc8] = pxh;
        *(bf16x8*)&XsL[srow * 40 + sc8] = pxl;
        int4 hw;
        hw.x = cvtpk(wf0.x, wf0.y);
        hw.y = cvtpk(wf0.z, wf0.w);
        hw.z = cvtpk(wf1.x, wf1.y);
        hw.w = cvtpk(wf1.z, wf1.w);
        int4 lw;
        lw.x = cvtpk(wf0.x - lobf(hw.x), wf0.y - hibf(hw.x));
        lw.y = cvtpk(wf0.z - lobf(hw.y), wf0.w - hibf(hw.y));
        lw.z = cvtpk(wf1.x - lobf(hw.z), wf1.y - hibf(hw.z));
        lw.w = cvtpk(wf1.z - lobf(hw.w), wf1.w - hibf(hw.w));
        *(int4*)&WsH[srow * 40 + sc8] = hw;
        *(int4*)&WsL[srow * 40 + sc8] = lw;
    };

    f32x4 acc[4];
#pragma unroll
    for (int n = 0; n < 4; ++n) acc[n] = (f32x4){0.f, 0.f, 0.f, 0.f};

    ld(0);
    for (int kc = 0; kc < DD; kc += 32) {
        __syncthreads();
        st();
        __syncthreads();
        if (kc + 32 < DD) ld(kc + 32);

        bf16x8 ah, al, bh[4], bl[4];
        ah = *(const bf16x8*)&XsH[(wid * 16 + c) * 40 + 8 * g];
        al = *(const bf16x8*)&XsL[(wid * 16 + c) * 40 + 8 * g];
#pragma unroll
        for (int n = 0; n < 4; ++n) {
            const int adr = (16 * n + c) * 40 + 8 * g;
            bh[n] = *(const bf16x8*)&WsH[adr];
            bl[n] = *(const bf16x8*)&WsL[adr];
        }
#pragma unroll
        for (int n = 0; n < 4; ++n) {
            acc[n] = MFMA16(ah, bh[n], acc[n]);
            acc[n] = MFMA16(ah, bl[n], acc[n]);
            acc[n] = MFMA16(al, bh[n], acc[n]);
        }
    }

#pragma unroll
    for (int n = 0; n < 4; ++n) {
        const int col = o0 + 16 * n + c;
        const float bo = b[col];
#pragma unroll
        for (int r = 0; r < 4; ++r)
            Y[(size_t)(r0 + wid * 16 + 4 * g + r) * DD + col] = acc[n][r] + bo;
    }
}

// ---------------------------------------------------------------------------
// MFMA flash attention (R14 config, best measured: attn 76.2 us).
// Swapped QK^T, in-register softmax, bias as MFMA C-in, l = P*ones MFMA,
// precomputed LDS pointers, per-wave LDS P-redistribute (no bpermute),
// defer-max, setprio. (512,4): VGPR cap 128 -- (512,8) spilled (R9);
// 2-q-group variants regressed (R15 spill at 64 VGPR, R16 occupancy 19%).
// ---------------------------------------------------------------------------
#define QT 128
#define KT 64
#define NKC 8
#define CHUNK (NLK / NKC)
#define NT (CHUNK / KT)

__global__ __launch_bounds__(512, 4) void attn_mfma(const short* __restrict__ qhi,
                                                    const short* __restrict__ khi,
                                                    const short* __restrict__ vthi,
                                                    const unsigned short* __restrict__ biash,
                                                    unsigned short* __restrict__ macc,
                                                    float2* __restrict__ mlb)
{
    __shared__ __align__(16) short ksh[2 * KT * HD];   // 16 KB
    __shared__ __align__(16) short vth[2 * KT * HD];   // 16 KB
    __shared__ __align__(16) short psh[8 * 16 * KT];   // 16 KB, per-wave 2 KB

    const int id = blockIdx.x;          // h*128 + qt*8 + kc
    const int h  = id >> 7;
    const int qt = (id >> 3) & 15;
    const int kc = id & 7;
    const int q0 = qt * QT;
    const int k0 = kc * CHUNK;

    const int t    = threadIdx.x;
    const int wid  = t >> 6;
    const int lane = t & 63;
    const int g  = lane >> 4;
    const int cl = lane & 15;
    const int swc = ((cl & 7) << 3);

    bf16x8 qah[2];
    {
        const size_t qr = (size_t)(q0 + wid * 16 + cl) * DD + h * HD;
        qah[0] = *(const bf16x8*)&qhi[qr + 8 * g];
        qah[1] = *(const bf16x8*)&qhi[qr + 32 + 8 * g];
    }

    const int v0 = (8 * g) ^ swc;
    const short* kbA0 = &ksh[cl * HD + v0];
    const short* kbB0 = &ksh[cl * HD + (v0 ^ 32)];
    const short* kbA1 = kbA0 + KT * HD;
    const short* kbB1 = kbB0 + KT * HD;
    const short* vbA0 = &vth[cl * HD + v0];
    const short* vbB0 = &vth[cl * HD + (v0 ^ 32)];
    const short* vbA1 = vbA0 + KT * HD;
    const short* vbB1 = vbB0 + KT * HD;

    const int kr0 = t >> 3;
    const int db0 = (t & 7) * 8;
    const int sw0 = ((kr0 & 7) << 3);
    short* wk0 = &ksh[kr0 * HD + (db0 ^ sw0)];
    short* wk1 = wk0 + KT * HD;
    short* wv0 = &vth[kr0 * HD + (db0 ^ sw0)];
    short* wv1 = wv0 + KT * HD;

    // per-wave P scratch: write 4x int2 (j=0..3), read 2x b128 (s=0..1).
    short* psw = &psh[wid * (16 * KT)];
    short* pw0 = &psw[cl * KT + (( 0 + 4 * g) ^ swc)];
    short* pw1 = &psw[cl * KT + ((16 + 4 * g) ^ swc)];
    short* pw2 = &psw[cl * KT + ((32 + 4 * g) ^ swc)];
    short* pw3 = &psw[cl * KT + ((48 + 4 * g) ^ swc)];
    const short* pr0 = &psw[cl * KT + ((8 * g) ^ swc)];
    const short* pr1 = &psw[cl * KT + ((32 + 8 * g) ^ swc)];

    const short* kgp = khi + (size_t)(k0 + kr0) * DD + h * HD + db0;
    const short* vgp = vthi + (size_t)(h * HD + kr0) * NLK + k0 + db0;
    const unsigned short* bgp =
        biash + (((size_t)(qt * 8 + wid) * 128 + kc * NT) << 10) + lane * 16;

    bf16x8 rkh, rvh;
    u16x8 bp0, bp1;
    rkh = *(const bf16x8*)kgp;  kgp += (size_t)KT * DD;
    rvh = *(const bf16x8*)vgp;  vgp += KT;
    bp0 = *(const u16x8*)bgp;
    bp1 = *(const u16x8*)(bgp + 8);  bgp += 1024;

    bf16x8 ones;
#pragma unroll
    for (int i = 0; i < 8; ++i) ones[i] = (short)0x3F80;

    f32x4 acco[4];
    f32x4 lacc = (f32x4){0.f, 0.f, 0.f, 0.f};
#pragma unroll
    for (int n = 0; n < 4; ++n) acco[n] = (f32x4){0.f, 0.f, 0.f, 0.f};
    float m_ = -1e30f;

    for (int it = 0; it < NT; ++it) {
        const int p = it & 1;
        const short* kA = p ? kbA1 : kbA0;
        const short* kB = p ? kbB1 : kbB0;
        const short* vA = p ? vbA1 : vbA0;
        const short* vB = p ? vbB1 : vbB0;
        short* wk = p ? wk1 : wk0;
        short* wv = p ? wv1 : wv0;

        *(bf16x8*)wk = rkh;
        *(bf16x8*)wv = rvh;
        __syncthreads();
        if (it + 1 < NT) {
            rkh = *(const bf16x8*)kgp;  kgp += (size_t)KT * DD;
            rvh = *(const bf16x8*)vgp;  vgp += KT;
        }

        // ---- C-in = bias fragment (mask + log2e prefolded) ----
        f32x4 sc[4];
#pragma unroll
        for (int j = 0; j < 4; ++j)
#pragma unroll
            for (int r = 0; r < 4; ++r) {
                const int i = j * 4 + r;
                sc[j][r] = h2f((i < 8) ? (unsigned short)bp0[i]
                                       : (unsigned short)bp1[i - 8]);
            }

        // ---- swapped QK^T accumulating onto bias ----
        __builtin_amdgcn_s_setprio(1);
#pragma unroll
        for (int j = 0; j < 4; ++j) {
            const bf16x8 kf0 = *(const bf16x8*)(kA + j * 16 * HD);
            const bf16x8 kf1 = *(const bf16x8*)(kB + j * 16 * HD);
            sc[j] = MFMA16(kf0, qah[0], sc[j]);
            sc[j] = MFMA16(kf1, qah[1], sc[j]);
        }
        __builtin_amdgcn_s_setprio(0);

        if (it + 1 < NT) {
            bp0 = *(const u16x8*)bgp;
            bp1 = *(const u16x8*)(bgp + 8);  bgp += 1024;
        }

        // ---- in-register softmax with defer-max (max3 trees) ----
        const float t0 = max3f(sc[0][0], sc[0][1], sc[0][2]);
        const float t1 = max3f(sc[0][3], sc[1][0], sc[1][1]);
        const float t2 = max3f(sc[1][2], sc[1][3], sc[2][0]);
        const float t3 = max3f(sc[2][1], sc[2][2], sc[2][3]);
        const float t4 = max3f(sc[3][0], sc[3][1], sc[3][2]);
        float tm = max3f(max3f(t0, t1, t2), max3f(t3, t4, sc[3][3]),
                         -1e30f);
        tm = fmaxf(tm, __shfl_xor(tm, 16));
        tm = fmaxf(tm, __shfl_xor(tm, 32));
        if (!__all(tm - m_ <= 11.5f)) {
            const float mn = fmaxf(m_, tm);
            const float al = exp2f(m_ - mn);
            float alr[4];
#pragma unroll
            for (int r = 0; r < 4; ++r) alr[r] = __shfl(al, 4 * g + r);
#pragma unroll
            for (int n = 0; n < 4; ++n)
#pragma unroll
                for (int r = 0; r < 4; ++r) acco[n][r] *= alr[r];
#pragma unroll
            for (int r = 0; r < 4; ++r) lacc[r] *= alr[r];
            m_ = mn;
        }
#pragma unroll
        for (int j = 0; j < 4; ++j)
#pragma unroll
            for (int r = 0; r < 4; ++r)
                sc[j][r] = exp2f(sc[j][r] - m_);

        // ---- pack P and redistribute via per-wave LDS (no barrier) ----
        *(int2*)pw0 = make_int2(cvtpk(sc[0][0], sc[0][1]), cvtpk(sc[0][2], sc[0][3]));
        *(int2*)pw1 = make_int2(cvtpk(sc[1][0], sc[1][1]), cvtpk(sc[1][2], sc[1][3]));
        *(int2*)pw2 = make_int2(cvtpk(sc[2][0], sc[2][1]), cvtpk(sc[2][2], sc[2][3]));
        *(int2*)pw3 = make_int2(cvtpk(sc[3][0], sc[3][1]), cvtpk(sc[3][2], sc[3][3]));
        bf16x8 pah[2];
        pah[0] = *(const bf16x8*)pr0;
        pah[1] = *(const bf16x8*)pr1;

        // ---- PV + l-sum (both on matrix pipe) ----
        __builtin_amdgcn_s_setprio(1);
#pragma unroll
        for (int n = 0; n < 4; ++n) {
            const bf16x8 vh0 = *(const bf16x8*)(vA + n * 16 * HD);
            const bf16x8 vh1 = *(const bf16x8*)(vB + n * 16 * HD);
            acco[n] = MFMA16(pah[0], vh0, acco[n]);
            acco[n] = MFMA16(pah[1], vh1, acco[n]);
        }
        lacc = MFMA16(pah[0], ones, lacc);
        lacc = MFMA16(pah[1], ones, lacc);
        __builtin_amdgcn_s_setprio(0);
    }

    // epilogue: normalize by 1/lacc[r] (same-lane, q = 4g+r aligned)
    f32x4 linv;
#pragma unroll
    for (int r = 0; r < 4; ++r) linv[r] = 1.f / lacc[r];
#pragma unroll
    for (int r = 0; r < 4; ++r) {
        const int q = q0 + wid * 16 + 4 * g + r;
        const size_t base = ((size_t)(kc * NH + h) * NLQ + q) * HD;
#pragma unroll
        for (int n = 0; n < 4; ++n)
            macc[base + 16 * n + cl] = f2h(acco[n][r] * linv[r]);
    }
    // route l[q=cl] to the g==0 store lane (m_ is already per q=cl)
    {
        const int srcl = ((cl >> 2) << 4) + cl;
        const float lc0 = __shfl(lacc[0], srcl);
        const float lc1 = __shfl(lacc[1], srcl);
        const float lc2 = __shfl(lacc[2], srcl);
        const float lc3 = __shfl(lacc[3], srcl);
        const int rr = cl & 3;
        const float lq = rr == 0 ? lc0 : rr == 1 ? lc1 : rr == 2 ? lc2 : lc3;
        if (g == 0)
            mlb[(size_t)(kc * NH + h) * NLQ + q0 + wid * 16 + cl] = make_float2(m_, lq);
    }
}

// ---------------------------------------------------------------------------
// Combine: partials pre-normalized; weight = exp2(m_c - M) * l_c.
// ---------------------------------------------------------------------------
__global__ __launch_bounds__(256) void attn_combine(const unsigned short* __restrict__ macc,
                                                    const float2* __restrict__ mlb,
                                                    short* __restrict__ aohi,
                                                    short* __restrict__ aolo)
{
    const int row = blockIdx.x * 4 + (threadIdx.x >> 6);  // h*NLQ + q
    const int d   = threadIdx.x & 63;
    float m[NKC], l[NKC];
#pragma unroll
    for (int c = 0; c < NKC; ++c) {
        const float2 v = mlb[(size_t)c * NH * NLQ + row];
        m[c] = v.x; l[c] = v.y;
    }
    float M = m[0];
#pragma unroll
    for (int c = 1; c < NKC; ++c) M = fmaxf(M, m[c]);
    float w[NKC], L = 0.f;
#pragma unroll
    for (int c = 0; c < NKC; ++c) { w[c] = exp2f(m[c] - M) * l[c]; L += w[c]; }
    float s = 0.f;
#pragma unroll
    for (int c = 0; c < NKC; ++c)
        s += h2f(macc[((size_t)c * NH * NLQ + row) * HD + d]) * w[c];
    const float v = s / L;
    const int hh = row >> 11;
    const int q  = row & (NLQ - 1);
    const size_t o = (size_t)q * DD + hh * HD + d;
    const unsigned short hb = f2bf(v);
    aohi[o] = (short)hb;
    aolo[o] = (short)f2bf(v - bf2f(hb));
}

extern "C" void kernel_launch(void* const* d_in, const int* in_sizes, int n_in,
                              void* d_out, int out_size, void* d_ws, size_t ws_size,
                              hipStream_t stream)
{
    (void)in_sizes; (void)n_in; (void)out_size; (void)ws_size;
    const float* Q    = (const float*)d_in[0];
    const float* K    = (const float*)d_in[1];
    const float* V    = (const float*)d_in[2];
    const int*   mask = (const int*)d_in[3];
    const float* bias = (const float*)d_in[4];
    const float* Win  = (const float*)d_in[5];
    const float* bin  = (const float*)d_in[6];
    const float* Wout = (const float*)d_in[7];
    const float* bout = (const float*)d_in[8];
    float* out = (float*)d_out;

    // ---- workspace (~72 MB flat) ----
    short* qhi_  = (short*)d_ws;                                // 2 MB
    short* khi_  = qhi_  + (size_t)NLQ * DD;                    // 8 MB
    short* vthi_ = khi_  + (size_t)NLK * DD;                    // 8 MB
    unsigned short* biash_ = (unsigned short*)(vthi_ + (size_t)NLK * DD); // 32 MB
    unsigned short* macc_  = biash_ + (size_t)NLQ * NLK;        // 16.8 MB
    float2* ml_  = (float2*)(macc_ + (size_t)NKC * NH * NLQ * HD);  // 1 MB
    short* aohi_ = (short*)(ml_ + (size_t)NKC * NH * NLQ);      // 2 MB
    short* aolo_ = aohi_ + (size_t)NLQ * DD;                    // 2 MB

    // 1) fused prep: QKV projection (576 blocks) + bias pack (4096 blocks)
    prep<<<dim3(NPROJ + 4096), 256, 0, stream>>>(Q, K, V, Win, bin, bias, mask,
                                                 qhi_, khi_, vthi_, biash_);

    // 2) attention (k-split NKC=8)
    attn_mfma<<<dim3(NH * 16 * NKC), 512, 0, stream>>>(qhi_, khi_, vthi_, biash_, macc_, ml_);

    // 3) combine partials -> ao (bf16 hi/lo)
    attn_combine<<<dim3(NH * NLQ / 4), 256, 0, stream>>>(macc_, ml_, aohi_, aolo_);

    // 4) out projection (W f32 staged)
    gemm_out<<<dim3(NLQ / 64, DD / 64), 256, 0, stream>>>(aohi_, aolo_, Wout, bout, out);
}